// Round 5
// baseline (4856.914 us; speedup 1.0000x reference)
//
#include <hip/hip_runtime.h>
#include <math.h>

#define BSZ 2048
#define DIM 2048
#define MS 6
#define NIT 29          // k = 1..29
#define LAMREG 1e-4f
#define XROWS (MS*DIM)  // 12288: row stride of the (bsz, 6, d) layouts
#define N2 ((size_t)BSZ*DIM)

typedef __bf16 bf16x8 __attribute__((ext_vector_type(8)));
typedef __bf16 bf16x4 __attribute__((ext_vector_type(4)));
typedef float  f32x4  __attribute__((ext_vector_type(4)));

__device__ __forceinline__ void async16(const void* g, void* l) {
    __builtin_amdgcn_global_load_lds((const __attribute__((address_space(1))) void*)g,
                                     (__attribute__((address_space(3))) void*)l, 16, 0, 0);
}

// swizzled LDS element offset for 16B chunk q (0..3) of row r in a [rows][32] bf16 panel
__device__ __forceinline__ int swz(int r, int q) {
    return r * 32 + ((q ^ ((r >> 1) & 3)) << 3);
}

__device__ __forceinline__ f32x4 fma4(float a, f32x4 x, f32x4 acc) {
    acc.x = fmaf(a, x.x, acc.x);
    acc.y = fmaf(a, x.y, acc.y);
    acc.z = fmaf(a, x.z, acc.z);
    acc.w = fmaf(a, x.w, acc.w);
    return acc;
}
__device__ __forceinline__ float dot4(f32x4 a, f32x4 b) {
    return a.x*b.x + a.y*b.y + a.z*b.z + a.w*b.w;
}

// ---------------------------------------------------------------------------
// init: X[:,0] = x0, split-bf16 copy of x0, zero norm buckets
// ---------------------------------------------------------------------------
__global__ __launch_bounds__(256) void init_kernel(const float* __restrict__ x0,
                                                   float* __restrict__ Xout,
                                                   __bf16* __restrict__ Ahi,
                                                   __bf16* __restrict__ Alo,
                                                   float* __restrict__ norms) {
    int idx = blockIdx.x * 256 + threadIdx.x;
    if (idx < 16 * NIT) norms[idx] = 0.0f;     // 8 buckets x {g2,f2} per iter
    for (int i = idx; i < BSZ * DIM; i += gridDim.x * 256) {
        int b = i >> 11;
        int j = i & (DIM - 1);
        float v = x0[i];
        Xout[(size_t)b * XROWS + j] = v;
        __bf16 h = (__bf16)v;
        Ahi[i] = h;
        Alo[i] = (__bf16)(v - (float)h);
    }
}

// ---------------------------------------------------------------------------
// W (K x N, f32) -> W^T split into bf16 hi/lo:  WT[n][k] = W[k][n]
// ---------------------------------------------------------------------------
__global__ __launch_bounds__(256) void wt_split_kernel(const float* __restrict__ W,
                                                       __bf16* __restrict__ WThi,
                                                       __bf16* __restrict__ WTlo) {
    __shared__ float tile[32][33];
    const int tx = threadIdx.x & 31;
    const int ty = threadIdx.x >> 5;
    const int n0 = blockIdx.x * 32;
    const int k0 = blockIdx.y * 32;
#pragma unroll
    for (int i = 0; i < 32; i += 8)
        tile[ty + i][tx] = W[(size_t)(k0 + ty + i) * DIM + n0 + tx];
    __syncthreads();
#pragma unroll
    for (int i = 0; i < 32; i += 8) {
        float v = tile[tx][ty + i];
        __bf16 h = (__bf16)v;
        size_t o = (size_t)(n0 + ty + i) * DIM + k0 + tx;
        WThi[o] = h;
        WTlo[o] = (__bf16)(v - (float)h);
    }
}

// ---------------------------------------------------------------------------
// split-bf16 MFMA GEMM, split-K=2: 128x128 tiles, each block does K=1024.
// (unchanged from R2 — measured ~38 us)
// ---------------------------------------------------------------------------
__global__ __launch_bounds__(256, 2) void gemm_mfma_kernel(
    const __bf16* __restrict__ Ahi, const __bf16* __restrict__ Alo,
    const __bf16* __restrict__ WThi, const __bf16* __restrict__ WTlo,
    float* __restrict__ P)
{
    __shared__ __align__(16) __bf16 Ah[2][128 * 32];
    __shared__ __align__(16) __bf16 Al[2][128 * 32];
    __shared__ __align__(16) __bf16 Bh[2][128 * 32];
    __shared__ __align__(16) __bf16 Bl[2][128 * 32];   // 64 KB -> 2 blocks/CU

    const int id = blockIdx.x;
    const int xcd = id & 7;
    const int rest = id >> 3;
    const int ks = rest >> 5;                  // K-half: 0 or 1
    const int slot = rest & 31;
    const int by = ((xcd & 3) << 2) | (slot & 3);      // 0..15
    const int bx = ((xcd >> 2) << 3) | (slot >> 2);    // 0..15
    const int m0 = by * 128;
    const int n0 = bx * 128;
    const int kbase = ks << 10;

    const int tid = threadIdx.x;
    const int l = tid & 63;
    const int w = tid >> 6;
    const int wm = (w & 1) * 64;    // wave's 64-row quadrant
    const int wn = (w >> 1) * 64;   // wave's 64-col quadrant
    const int rl = l & 15;
    const int quad = l >> 4;

    const int srow = w * 16 + (l >> 2);
    const int gchunk = (l & 3) ^ ((l >> 3) & 3);
    const int scol = gchunk << 3;
    const size_t aoff = (size_t)(m0 + srow) * DIM + kbase + scol;
    const size_t boff = (size_t)(n0 + srow) * DIM + kbase + scol;
    const int lo = w * 512;

    f32x4 acc[4][4];
#pragma unroll
    for (int t = 0; t < 4; t++)
#pragma unroll
        for (int u = 0; u < 4; u++) acc[t][u] = (f32x4){0.f, 0.f, 0.f, 0.f};

    auto stage = [&](int kb, int s) {
        async16(Ahi + aoff + kb, &Ah[s][lo]);
        async16(Ahi + aoff + (size_t)64 * DIM + kb, &Ah[s][lo + 2048]);
        async16(Alo + aoff + kb, &Al[s][lo]);
        async16(Alo + aoff + (size_t)64 * DIM + kb, &Al[s][lo + 2048]);
        async16(WThi + boff + kb, &Bh[s][lo]);
        async16(WThi + boff + (size_t)64 * DIM + kb, &Bh[s][lo + 2048]);
        async16(WTlo + boff + kb, &Bl[s][lo]);
        async16(WTlo + boff + (size_t)64 * DIM + kb, &Bl[s][lo + 2048]);
    };
    auto compute = [&](int s) {
        bf16x8 ah[4], al[4];
#pragma unroll
        for (int t = 0; t < 4; t++) {
            const int r = wm + t * 16 + rl;
            ah[t] = *(const bf16x8*)&Ah[s][swz(r, quad)];
            al[t] = *(const bf16x8*)&Al[s][swz(r, quad)];
        }
#pragma unroll
        for (int u = 0; u < 4; u++) {
            const int c = wn + u * 16 + rl;
            bf16x8 bh = *(const bf16x8*)&Bh[s][swz(c, quad)];
            bf16x8 bl = *(const bf16x8*)&Bl[s][swz(c, quad)];
#pragma unroll
            for (int t = 0; t < 4; t++) {
                acc[t][u] = __builtin_amdgcn_mfma_f32_16x16x32_bf16(ah[t], bh, acc[t][u], 0, 0, 0);
                acc[t][u] = __builtin_amdgcn_mfma_f32_16x16x32_bf16(al[t], bh, acc[t][u], 0, 0, 0);
                acc[t][u] = __builtin_amdgcn_mfma_f32_16x16x32_bf16(ah[t], bl, acc[t][u], 0, 0, 0);
            }
        }
    };

    stage(0, 0);
    for (int k0 = 0; k0 < 1024; k0 += 64) {
        __syncthreads();               // drains buf0 loads (issued one phase ago)
        stage(k0 + 32, 1);
        compute(0);
        __syncthreads();               // drains buf1 loads
        if (k0 + 64 < 1024) stage(k0 + 64, 0);
        compute(1);
    }

    // write f32 partial tile to P[ks]
    float* Pk = P + (size_t)ks * N2;
#pragma unroll
    for (int t = 0; t < 4; t++) {
#pragma unroll
        for (int r = 0; r < 4; r++) {
            const int row = m0 + wm + t * 16 + quad * 4 + r;
            float* pr = Pk + (size_t)row * DIM + n0 + wn;
#pragma unroll
            for (int u = 0; u < 4; u++) pr[u * 16 + rl] = acc[t][u][r];
        }
    }
}

// ---------------------------------------------------------------------------
// mega R4b: ONE WAVE PER BATCH ROW, zero __syncthreads.
// 64 lanes x 8 f32x4 chunks = one 2048-wide row. Reduction = shfl_xor
// butterfly (every lane ends with all 8 sums -> solve build is pure static
// register ops). 7x7 bordered solve lane-parallel in-wave. Waves drift
// independently -> memory pipes stay fed while any wave solves.
// R4b fix: no runtime-indexed register-array writes (rule #20 scratch trap).
// ---------------------------------------------------------------------------
__global__ __launch_bounds__(256) void mega_kernel(
    const float* __restrict__ P, const float* __restrict__ bias,
    float* __restrict__ Fb, float* __restrict__ Xb, float* __restrict__ Gb,
    float* __restrict__ GGt,
    __bf16* __restrict__ Ahi, __bf16* __restrict__ Alo,
    float* __restrict__ resultOrNull, float* __restrict__ normAcc,
    int up, int nact, int nxt)
{
    const int wave = threadIdx.x >> 6;
    const int l = threadIdx.x & 63;
    const int b = blockIdx.x * 4 + wave;
    const size_t rb = (size_t)b * XROWS;
    const size_t prow = (size_t)b * DIM;

    const f32x4* P0 = (const f32x4*)(P + prow);
    const f32x4* P1 = (const f32x4*)(P + N2 + prow);
    const f32x4* Bi = (const f32x4*)bias;
    const f32x4* Xu = (const f32x4*)(Xb + rb + (size_t)up * DIM);
    f32x4* Fu = (f32x4*)(Fb + rb + (size_t)up * DIM);
    f32x4* Gu = Gb ? (f32x4*)(Gb + rb + (size_t)up * DIM) : nullptr;
    float* gg = GGt + (size_t)b * 36;

    // early: old Gram row for lane a = l-1 (clamped; only lanes 1..6 use it)
    float grow[6];
    {
        const int a = l - 1;
        const int aa = (a >= 0 && a < 6) ? a : 0;
#pragma unroll
        for (int c = 0; c < 6; c++) grow[c] = gg[aa * 6 + c];
    }

    // ---- phase 1: epilogue (chunk-major; fv/gv stay live) ----
    f32x4 fv[8], gv[8];
    float s1 = 0.f, s2 = 0.f;
#pragma unroll
    for (int c = 0; c < 8; c++) {
        const int idx = l + 64 * c;
        f32x4 z = P0[idx] + P1[idx] + Bi[idx];
        f32x4 t;
        t.x = tanhf(z.x); t.y = tanhf(z.y); t.z = tanhf(z.z); t.w = tanhf(z.w);
        f32x4 xv = Xu[idx];
        f32x4 g = t - xv;
        fv[c] = t; gv[c] = g;
        Fu[idx] = t;
        if (Gu) Gu[idx] = g;
        s1 += dot4(g, g);
        s2 += dot4(t, t);
    }

    // ---- phase 2: dots (chunk-major, 5 independent loads per chunk) ----
    float acc[8];
#pragma unroll
    for (int p = 0; p < MS; p++) acc[p] = 0.f;
    acc[6] = s1; acc[7] = s2;

    if (Gb) {
#pragma unroll
        for (int c = 0; c < 8; c++) {
            const int idx = l + 64 * c;
#pragma unroll
            for (int j = 0; j < MS; j++) {
                if (j < nact && j != up) {
                    f32x4 gj = ((const f32x4*)(Gb + rb + (size_t)j * DIM))[idx];
                    acc[j] += dot4(gv[c], gj);
                }
            }
        }
    } else {
#pragma unroll
        for (int c = 0; c < 8; c++) {
            const int idx = l + 64 * c;
#pragma unroll
            for (int j = 0; j < MS; j++) {
                if (j < nact && j != up) {
                    f32x4 fj = ((const f32x4*)(Fb + rb + (size_t)j * DIM))[idx];
                    f32x4 xj = ((const f32x4*)(Xb + rb + (size_t)j * DIM))[idx];
                    acc[j] += dot4(gv[c], fj - xj);
                }
            }
        }
    }
    // static-index write of acc[up] = s1 (runtime index would demote acc to scratch)
#pragma unroll
    for (int j = 0; j < MS; j++)
        if (j == up) acc[j] = s1;

    // ---- wave butterfly reduce: every lane gets all 8 sums ----
#pragma unroll
    for (int p = 0; p < 8; p++) {
        float v = acc[p];
#pragma unroll
        for (int off = 32; off > 0; off >>= 1) v += __shfl_xor(v, off);
        acc[p] = v;
    }

    if (normAcc) {
        if (l == 0) atomicAdd(&normAcc[b & 7], acc[6]);
        if (l == 1) atomicAdd(&normAcc[8 + (b & 7)], acc[7]);
    }

    // ---- phase 3: Gram write + lane-parallel bordered solve ----
    float sol[7];
#pragma unroll
    for (int p = 0; p < 7; p++) sol[p] = 0.f;

    if (nact > 0) {
        // static-index select chains (no runtime reg indexing -> no scratch)
        const int a = l - 1;
        float accl = (l == 0) ? acc[0] : (l == 1) ? acc[1] : (l == 2) ? acc[2]
                   : (l == 3) ? acc[3] : (l == 4) ? acc[4] : (l == 5) ? acc[5] : 0.f;
        float acca = (a == 0) ? acc[0] : (a == 1) ? acc[1] : (a == 2) ? acc[2]
                   : (a == 3) ? acc[3] : (a == 4) ? acc[4] : (a == 5) ? acc[5] : 0.f;
        if (l < nact) {
            gg[up * 6 + l] = accl;
            gg[l * 6 + up] = accl;
        }
        const int np = nact + 1;
        // build bordered system; lane i holds row i: r[0..6] = H, r[7] = rhs
        float r[8];
        {
            const int i = l;
            r[0] = (i == 0) ? 0.f : 1.f;
#pragma unroll
            for (int j = 1; j < 7; j++) {
                const int c = j - 1;
                float v;
                if (i == 0) v = 1.f;
                else v = (a == up) ? acc[c] : ((c == up) ? acca : grow[c]);
                if (i == j) v += LAMREG;
                r[j] = v;
            }
            r[7] = (i == 0) ? 1.f : 0.f;
        }
        // Gaussian elimination with partial pivoting, lane-parallel
#pragma unroll
        for (int c = 0; c < 7; c++) {
            if (c < np) {
                float key = (l >= c && l < np) ? fabsf(r[c]) : -1.f;
                int idx = l;
#pragma unroll
                for (int off = 32; off > 0; off >>= 1) {
                    float ok = __shfl_xor(key, off);
                    int oi = __shfl_xor(idx, off);
                    if (ok > key || (ok == key && oi < idx)) { key = ok; idx = oi; }
                }
                const int src = (l == c) ? idx : ((l == idx) ? c : l);
#pragma unroll
                for (int k = 0; k < 8; k++) r[k] = __shfl(r[k], src);
                float pr[8];
#pragma unroll
                for (int k = 0; k < 8; k++) pr[k] = __shfl(r[k], c);
                const float inv = 1.f / pr[c];
                const float f = (l > c && l < np) ? r[c] * inv : 0.f;
#pragma unroll
                for (int k = 0; k < 8; k++) r[k] = fmaf(-f, pr[k], r[k]);
            }
        }
        // back substitution; after each step every lane holds sol[c]
#pragma unroll
        for (int c = 6; c >= 0; c--) {
            if (c < np) {
                float s = r[7];
#pragma unroll
                for (int cc = 6; cc > 0; cc--)
                    if (cc > c && cc < np) s = fmaf(-r[cc], sol[cc], s);
                s /= r[c];
                sol[c] = __shfl(s, c);
            }
        }
    }

    // ---- phase 4: xnew (chunk-major; alpha_j = sol[j+1], static index) ----
    if (nxt >= 0) {
        f32x4* Xn = (f32x4*)(Xb + rb + (size_t)nxt * DIM);
#pragma unroll
        for (int c = 0; c < 8; c++) {
            const int idx = l + 64 * c;
            f32x4 s = (f32x4){0.f, 0.f, 0.f, 0.f};
#pragma unroll
            for (int j = 0; j < MS; j++) {
                if (j < nact) {
                    const float a = sol[j + 1];
                    if (j == up) {
                        s = fma4(a, fv[c], s);
                    } else {
                        f32x4 fj = ((const f32x4*)(Fb + rb + (size_t)j * DIM))[idx];
                        s = fma4(a, fj, s);
                    }
                }
            }
            Xn[idx] = s;
            if (resultOrNull) ((f32x4*)(resultOrNull + prow))[idx] = s;
            bf16x4 hh, ll;
#pragma unroll
            for (int q = 0; q < 4; q++) {
                float v = s[q];
                __bf16 h = (__bf16)v;
                hh[q] = h;
                ll[q] = (__bf16)(v - (float)h);
            }
            *(bf16x4*)&Ahi[prow + (size_t)idx * 4] = hh;
            *(bf16x4*)&Alo[prow + (size_t)idx * 4] = ll;
        }
    }
}

__global__ void finalize_kernel(const float* __restrict__ norms,
                                float* __restrict__ rel, float* __restrict__ absd)
{
    int t = threadIdx.x;
    if (t < NIT) {
        float a2 = 0.f, f2 = 0.f;
        for (int i = 0; i < 8; i++) {
            a2 += norms[t * 16 + i];
            f2 += norms[t * 16 + 8 + i];
        }
        float a = sqrtf(a2);
        absd[t] = a;
        rel[t] = a / (1e-5f + sqrtf(f2));
    }
}

extern "C" void kernel_launch(void* const* d_in, const int* in_sizes, int n_in,
                              void* d_out, int out_size, void* d_ws, size_t ws_size,
                              hipStream_t stream) {
    const float* x0   = (const float*)d_in[0];
    const float* W    = (const float*)d_in[1];
    const float* bias = (const float*)d_in[2];

    float* out    = (float*)d_out;
    float* result = out;
    float* Xout   = out + (size_t)BSZ * DIM;
    float* rel    = Xout + (size_t)BSZ * MS * DIM;
    float* absd   = rel + NIT;

    char* ws = (char*)d_ws;
    float* F     = (float*)ws;                                   // 100.66 MB
    float* norms = F + (size_t)BSZ * MS * DIM;                   // 2 KB (16*NIT used)
    float* GGt   = norms + 512;                                  // 288 KB
    float* P     = GGt + (size_t)BSZ * 36;                       // 33.55 MB (2 planes)
    char* p = (char*)(P + 2 * N2);
    size_t off = ((size_t)(p - ws) + 255) & ~(size_t)255;
    __bf16* Ahi  = (__bf16*)(ws + off);  off += (size_t)BSZ * DIM * 2;
    __bf16* Alo  = (__bf16*)(ws + off);  off += (size_t)BSZ * DIM * 2;
    __bf16* WThi = (__bf16*)(ws + off);  off += (size_t)DIM * DIM * 2;
    __bf16* WTlo = (__bf16*)(ws + off);  off += (size_t)DIM * DIM * 2;
    // G array (100.66 MB) only if scratch is big enough
    float* G = nullptr;
    if (ws_size >= off + (size_t)BSZ * MS * DIM * 4 + 256) {
        off = (off + 255) & ~(size_t)255;
        G = (float*)(ws + off);
    }

    wt_split_kernel<<<dim3(64, 64), 256, 0, stream>>>(W, WThi, WTlo);
    init_kernel<<<2048, 256, 0, stream>>>(x0, Xout, Ahi, Alo, norms);

    // mega_j consumes gemm_j's P (f(arg_j)) and produces xnew_{j+1}:
    //   j=0:   arg = x0            (norms not traced)
    //   j>=1:  arg = xnew_j        (norms -> iter j)
    for (int j = 0; j <= NIT; j++) {
        gemm_mfma_kernel<<<512, 256, 0, stream>>>(Ahi, Alo, WThi, WTlo, P);
        int up   = j % MS;
        int nact = (j < NIT) ? ((j + 1 < MS) ? (j + 1) : MS) : 0;
        int nxt  = (j < NIT) ? ((j + 1) % MS) : -1;
        mega_kernel<<<BSZ / 4, 256, 0, stream>>>(P, bias, F, Xout, G, GGt, Ahi, Alo,
                                                 (j == NIT - 1) ? result : nullptr,
                                                 (j >= 1) ? (norms + 16 * (j - 1)) : nullptr,
                                                 up, nact, nxt);
    }
    finalize_kernel<<<1, 64, 0, stream>>>(norms, rel, absd);
}

// Round 7
// 3861.785 us; speedup vs baseline: 1.2577x; 1.2577x over previous
//
#include <hip/hip_runtime.h>
#include <math.h>

#define BSZ 2048
#define DIM 2048
#define MS 6
#define NIT 29          // k = 1..29
#define LAMREG 1e-4f
#define XROWS (MS*DIM)  // 12288: row stride of the (bsz, 6, d) layouts
#define N2 ((size_t)BSZ*DIM)

typedef __bf16 bf16x8 __attribute__((ext_vector_type(8)));
typedef __bf16 bf16x4 __attribute__((ext_vector_type(4)));
typedef float  f32x4  __attribute__((ext_vector_type(4)));

__device__ __forceinline__ void async16(const void* g, void* l) {
    __builtin_amdgcn_global_load_lds((const __attribute__((address_space(1))) void*)g,
                                     (__attribute__((address_space(3))) void*)l, 16, 0, 0);
}

// swizzled LDS element offset for 16B chunk q (0..3) of row r in a [rows][32] bf16 panel
__device__ __forceinline__ int swz(int r, int q) {
    return r * 32 + ((q ^ ((r >> 1) & 3)) << 3);
}

__device__ __forceinline__ f32x4 fma4(float a, f32x4 x, f32x4 acc) {
    acc.x = fmaf(a, x.x, acc.x);
    acc.y = fmaf(a, x.y, acc.y);
    acc.z = fmaf(a, x.z, acc.z);
    acc.w = fmaf(a, x.w, acc.w);
    return acc;
}
__device__ __forceinline__ float dot4(f32x4 a, f32x4 b) {
    return a.x*b.x + a.y*b.y + a.z*b.z + a.w*b.w;
}
__device__ __forceinline__ float dot8(f32x4 u0, f32x4 u1, f32x4 a, f32x4 b) {
    return dot4(u0, a) + dot4(u1, b);
}

// ---------------------------------------------------------------------------
// init: X[:,0] = x0, split-bf16 copy of x0, zero norm buckets
// ---------------------------------------------------------------------------
__global__ __launch_bounds__(256) void init_kernel(const float* __restrict__ x0,
                                                   float* __restrict__ Xout,
                                                   __bf16* __restrict__ Ahi,
                                                   __bf16* __restrict__ Alo,
                                                   float* __restrict__ norms) {
    int idx = blockIdx.x * 256 + threadIdx.x;
    if (idx < 16 * NIT) norms[idx] = 0.0f;     // 8 buckets x {g2,f2} per iter
    for (int i = idx; i < BSZ * DIM; i += gridDim.x * 256) {
        int b = i >> 11;
        int j = i & (DIM - 1);
        float v = x0[i];
        Xout[(size_t)b * XROWS + j] = v;
        __bf16 h = (__bf16)v;
        Ahi[i] = h;
        Alo[i] = (__bf16)(v - (float)h);
    }
}

// ---------------------------------------------------------------------------
// W (K x N, f32) -> W^T split into bf16 hi/lo:  WT[n][k] = W[k][n]
// ---------------------------------------------------------------------------
__global__ __launch_bounds__(256) void wt_split_kernel(const float* __restrict__ W,
                                                       __bf16* __restrict__ WThi,
                                                       __bf16* __restrict__ WTlo) {
    __shared__ float tile[32][33];
    const int tx = threadIdx.x & 31;
    const int ty = threadIdx.x >> 5;
    const int n0 = blockIdx.x * 32;
    const int k0 = blockIdx.y * 32;
#pragma unroll
    for (int i = 0; i < 32; i += 8)
        tile[ty + i][tx] = W[(size_t)(k0 + ty + i) * DIM + n0 + tx];
    __syncthreads();
#pragma unroll
    for (int i = 0; i < 32; i += 8) {
        float v = tile[tx][ty + i];
        __bf16 h = (__bf16)v;
        size_t o = (size_t)(n0 + ty + i) * DIM + k0 + tx;
        WThi[o] = h;
        WTlo[o] = (__bf16)(v - (float)h);
    }
}

// ---------------------------------------------------------------------------
// split-bf16 MFMA GEMM, split-K=2: 128x128 tiles, each block does K=1024.
// (unchanged from R2 — measured ~38 us)
// ---------------------------------------------------------------------------
__global__ __launch_bounds__(256, 2) void gemm_mfma_kernel(
    const __bf16* __restrict__ Ahi, const __bf16* __restrict__ Alo,
    const __bf16* __restrict__ WThi, const __bf16* __restrict__ WTlo,
    float* __restrict__ P)
{
    __shared__ __align__(16) __bf16 Ah[2][128 * 32];
    __shared__ __align__(16) __bf16 Al[2][128 * 32];
    __shared__ __align__(16) __bf16 Bh[2][128 * 32];
    __shared__ __align__(16) __bf16 Bl[2][128 * 32];   // 64 KB -> 2 blocks/CU

    const int id = blockIdx.x;
    const int xcd = id & 7;
    const int rest = id >> 3;
    const int ks = rest >> 5;                  // K-half: 0 or 1
    const int slot = rest & 31;
    const int by = ((xcd & 3) << 2) | (slot & 3);      // 0..15
    const int bx = ((xcd >> 2) << 3) | (slot >> 2);    // 0..15
    const int m0 = by * 128;
    const int n0 = bx * 128;
    const int kbase = ks << 10;

    const int tid = threadIdx.x;
    const int l = tid & 63;
    const int w = tid >> 6;
    const int wm = (w & 1) * 64;    // wave's 64-row quadrant
    const int wn = (w >> 1) * 64;   // wave's 64-col quadrant
    const int rl = l & 15;
    const int quad = l >> 4;

    const int srow = w * 16 + (l >> 2);
    const int gchunk = (l & 3) ^ ((l >> 3) & 3);
    const int scol = gchunk << 3;
    const size_t aoff = (size_t)(m0 + srow) * DIM + kbase + scol;
    const size_t boff = (size_t)(n0 + srow) * DIM + kbase + scol;
    const int lo = w * 512;

    f32x4 acc[4][4];
#pragma unroll
    for (int t = 0; t < 4; t++)
#pragma unroll
        for (int u = 0; u < 4; u++) acc[t][u] = (f32x4){0.f, 0.f, 0.f, 0.f};

    auto stage = [&](int kb, int s) {
        async16(Ahi + aoff + kb, &Ah[s][lo]);
        async16(Ahi + aoff + (size_t)64 * DIM + kb, &Ah[s][lo + 2048]);
        async16(Alo + aoff + kb, &Al[s][lo]);
        async16(Alo + aoff + (size_t)64 * DIM + kb, &Al[s][lo + 2048]);
        async16(WThi + boff + kb, &Bh[s][lo]);
        async16(WThi + boff + (size_t)64 * DIM + kb, &Bh[s][lo + 2048]);
        async16(WTlo + boff + kb, &Bl[s][lo]);
        async16(WTlo + boff + (size_t)64 * DIM + kb, &Bl[s][lo + 2048]);
    };
    auto compute = [&](int s) {
        bf16x8 ah[4], al[4];
#pragma unroll
        for (int t = 0; t < 4; t++) {
            const int r = wm + t * 16 + rl;
            ah[t] = *(const bf16x8*)&Ah[s][swz(r, quad)];
            al[t] = *(const bf16x8*)&Al[s][swz(r, quad)];
        }
#pragma unroll
        for (int u = 0; u < 4; u++) {
            const int c = wn + u * 16 + rl;
            bf16x8 bh = *(const bf16x8*)&Bh[s][swz(c, quad)];
            bf16x8 bl = *(const bf16x8*)&Bl[s][swz(c, quad)];
#pragma unroll
            for (int t = 0; t < 4; t++) {
                acc[t][u] = __builtin_amdgcn_mfma_f32_16x16x32_bf16(ah[t], bh, acc[t][u], 0, 0, 0);
                acc[t][u] = __builtin_amdgcn_mfma_f32_16x16x32_bf16(al[t], bh, acc[t][u], 0, 0, 0);
                acc[t][u] = __builtin_amdgcn_mfma_f32_16x16x32_bf16(ah[t], bl, acc[t][u], 0, 0, 0);
            }
        }
    };

    stage(0, 0);
    for (int k0 = 0; k0 < 1024; k0 += 64) {
        __syncthreads();               // drains buf0 loads (issued one phase ago)
        stage(k0 + 32, 1);
        compute(0);
        __syncthreads();               // drains buf1 loads
        if (k0 + 64 < 1024) stage(k0 + 64, 0);
        compute(1);
    }

    // write f32 partial tile to P[ks]
    float* Pk = P + (size_t)ks * N2;
#pragma unroll
    for (int t = 0; t < 4; t++) {
#pragma unroll
        for (int r = 0; r < 4; r++) {
            const int row = m0 + wm + t * 16 + quad * 4 + r;
            float* pr = Pk + (size_t)row * DIM + n0 + wn;
#pragma unroll
            for (int u = 0; u < 4; u++) pr[u * 16 + rl] = acc[t][u][r];
        }
    }
}

// ---------------------------------------------------------------------------
// mega R6b: block-per-row (2048 blocks, 8/CU), ONE barrier, no post-barrier
// global loads.
//   pre-barrier: epilogue loads + dots G-loads + xnew F-prefetch (T14),
//                butterfly reduce, LDS exchange of 4x8 partials
//   barrier
//   post-barrier: all 4 waves redundantly lane-parallel 7x7 solve (~400cy),
//                 xnew from prefetched regs (pure FMA + stores)
// R6b: fja/fjb zero-initialized (remove the only undefined-value path).
// ---------------------------------------------------------------------------
__global__ __launch_bounds__(256) void mega_kernel(
    const float* __restrict__ P, const float* __restrict__ bias,
    float* __restrict__ Fb, float* __restrict__ Xb, float* __restrict__ Gb,
    float* __restrict__ GGt,
    __bf16* __restrict__ Ahi, __bf16* __restrict__ Alo,
    float* __restrict__ resultOrNull, float* __restrict__ normAcc,
    int up, int nact, int nxt)
{
    const int b = blockIdx.x;
    const int tid = threadIdx.x;
    const int lane = tid & 63, wave = tid >> 6;
    const size_t rb = (size_t)b * XROWS;
    const size_t prow = (size_t)b * DIM;
    const int t0 = tid, t1 = tid + 256;

    float* gg = GGt + (size_t)b * 36;
    // old Gram row for lane a = lane-1 (clamped; only rows 1..6 use it)
    float grow[6];
    {
        const int a = lane - 1;
        const int aa = (a >= 0 && a < 6) ? a : 0;
#pragma unroll
        for (int c = 0; c < 6; c++) grow[c] = gg[aa * 6 + c];
    }

    const f32x4* P0 = (const f32x4*)(P + prow);
    const f32x4* P1 = (const f32x4*)(P + N2 + prow);
    const f32x4* Bi = (const f32x4*)bias;
    const f32x4* Xu = (const f32x4*)(Xb + rb + (size_t)up * DIM);
    f32x4* Fu = (f32x4*)(Fb + rb + (size_t)up * DIM);
    f32x4* Gu = Gb ? (f32x4*)(Gb + rb + (size_t)up * DIM) : nullptr;

    // ---- phase 1: epilogue ----
    f32x4 fv[2], gv[2];
    float s1 = 0.f, s2 = 0.f;
#pragma unroll
    for (int i = 0; i < 2; i++) {
        const int p4 = tid + 256 * i;
        f32x4 z = P0[p4] + P1[p4] + Bi[p4];
        f32x4 t;
        t.x = tanhf(z.x); t.y = tanhf(z.y); t.z = tanhf(z.z); t.w = tanhf(z.w);
        f32x4 xv = Xu[p4];
        f32x4 g = t - xv;
        fv[i] = t; gv[i] = g;
        Fu[p4] = t;
        if (Gu) Gu[p4] = g;
        s1 += dot4(g, g);
        s2 += dot4(t, t);
    }

    // ---- phase 2: dots (G loads) ----
    float acc6[6];
#pragma unroll
    for (int p = 0; p < 6; p++) acc6[p] = 0.f;

    if (Gb) {
#pragma unroll
        for (int j = 0; j < MS; j++) {
            if (j < nact && j != up) {
                const f32x4* Gj = (const f32x4*)(Gb + rb + (size_t)j * DIM);
                f32x4 ga = Gj[t0], gb = Gj[t1];
                acc6[j] = dot8(gv[0], gv[1], ga, gb);
            }
        }
    } else {
#pragma unroll
        for (int j = 0; j < MS; j++) {
            if (j < nact && j != up) {
                const f32x4* Fj = (const f32x4*)(Fb + rb + (size_t)j * DIM);
                const f32x4* Xj = (const f32x4*)(Xb + rb + (size_t)j * DIM);
                f32x4 ga = Fj[t0] - Xj[t0], gb = Fj[t1] - Xj[t1];
                acc6[j] = dot8(gv[0], gv[1], ga, gb);
            }
        }
    }
    // static-index write of acc6[up] = s1 (runtime index -> scratch trap)
#pragma unroll
    for (int j = 0; j < MS; j++)
        if (j == up) acc6[j] = s1;

    // ---- T14 prefetch: xnew F-planes (consumed after barrier, no loads there)
    f32x4 fja[6], fjb[6];   // static-indexed only (full unroll)
#pragma unroll
    for (int j = 0; j < MS; j++) {
        fja[j] = (f32x4){0.f, 0.f, 0.f, 0.f};
        fjb[j] = (f32x4){0.f, 0.f, 0.f, 0.f};
    }
    if (nxt >= 0) {
#pragma unroll
        for (int j = 0; j < MS; j++) {
            if (j < nact && j != up) {
                const f32x4* Fj = (const f32x4*)(Fb + rb + (size_t)j * DIM);
                fja[j] = Fj[t0];
                fjb[j] = Fj[t1];
            }
        }
    }

    // ---- butterfly reduce 8 values in-wave ----
#pragma unroll
    for (int p = 0; p < 6; p++) {
        float v = acc6[p];
#pragma unroll
        for (int off = 32; off > 0; off >>= 1) v += __shfl_xor(v, off);
        acc6[p] = v;
    }
#pragma unroll
    for (int off = 32; off > 0; off >>= 1) s1 += __shfl_xor(s1, off);
#pragma unroll
    for (int off = 32; off > 0; off >>= 1) s2 += __shfl_xor(s2, off);

    __shared__ float red[4][8];
    if (lane == 0) {
#pragma unroll
        for (int p = 0; p < 6; p++) red[wave][p] = acc6[p];
        red[wave][6] = s1;
        red[wave][7] = s2;
    }
    __syncthreads();               // the ONLY barrier

    float d[8];
#pragma unroll
    for (int p = 0; p < 8; p++)
        d[p] = red[0][p] + red[1][p] + red[2][p] + red[3][p];

    if (normAcc && wave == 0) {
        if (lane == 0) atomicAdd(&normAcc[b & 7], d[6]);
        if (lane == 1) atomicAdd(&normAcc[8 + (b & 7)], d[7]);
    }

    // ---- solve: all 4 waves redundantly, lane-parallel over rows ----
    float sol[7];
#pragma unroll
    for (int p = 0; p < 7; p++) sol[p] = 0.f;

    if (nact > 0) {
        // persist new Gram row/col (wave 0 only; static select for d[lane])
        if (wave == 0 && lane < nact) {
            float dl = (lane == 0) ? d[0] : (lane == 1) ? d[1] : (lane == 2) ? d[2]
                     : (lane == 3) ? d[3] : (lane == 4) ? d[4] : d[5];
            gg[up * 6 + lane] = dl;
            gg[lane * 6 + up] = dl;
        }
        const int a = lane - 1;
        float da = (a == 0) ? d[0] : (a == 1) ? d[1] : (a == 2) ? d[2]
                 : (a == 3) ? d[3] : (a == 4) ? d[4] : (a == 5) ? d[5] : 0.f;
        const int np = nact + 1;
        // lane i holds row i of the bordered system: r[0..6] = H, r[7] = rhs
        float r[8];
        r[0] = (lane == 0) ? 0.f : 1.f;
#pragma unroll
        for (int j = 1; j < 7; j++) {
            const int c = j - 1;
            float v;
            if (lane == 0) v = 1.f;
            else v = (a == up) ? d[c] : ((c == up) ? da : grow[c]);
            if (lane == j) v += LAMREG;
            r[j] = v;
        }
        r[7] = (lane == 0) ? 1.f : 0.f;
        // Gaussian elimination with partial pivoting, lane-parallel
#pragma unroll
        for (int c = 0; c < 7; c++) {
            if (c < np) {
                float key = (lane >= c && lane < np) ? fabsf(r[c]) : -1.f;
                int idx = lane;
#pragma unroll
                for (int off = 32; off > 0; off >>= 1) {
                    float ok = __shfl_xor(key, off);
                    int oi = __shfl_xor(idx, off);
                    if (ok > key || (ok == key && oi < idx)) { key = ok; idx = oi; }
                }
                const int src = (lane == c) ? idx : ((lane == idx) ? c : lane);
#pragma unroll
                for (int k = 0; k < 8; k++) r[k] = __shfl(r[k], src);
                float pr[8];
#pragma unroll
                for (int k = 0; k < 8; k++) pr[k] = __shfl(r[k], c);
                const float inv = 1.f / pr[c];
                const float f = (lane > c && lane < np) ? r[c] * inv : 0.f;
#pragma unroll
                for (int k = 0; k < 8; k++) r[k] = fmaf(-f, pr[k], r[k]);
            }
        }
        // back substitution; after each step every lane holds sol[c]
#pragma unroll
        for (int c = 6; c >= 0; c--) {
            if (c < np) {
                float s = r[7];
#pragma unroll
                for (int cc = 6; cc > 0; cc--)
                    if (cc > c && cc < np) s = fmaf(-r[cc], sol[cc], s);
                s /= r[c];
                sol[c] = __shfl(s, c);
            }
        }
    }

    // ---- phase 4: xnew from prefetched registers (no global loads) ----
    if (nxt >= 0) {
        f32x4* Xn = (f32x4*)(Xb + rb + (size_t)nxt * DIM);
        f32x4 sa = (f32x4){0.f, 0.f, 0.f, 0.f};
        f32x4 sb = (f32x4){0.f, 0.f, 0.f, 0.f};
#pragma unroll
        for (int j = 0; j < MS; j++) {
            if (j < nact) {
                const float aco = sol[j + 1];
                if (j == up) {
                    sa = fma4(aco, fv[0], sa);
                    sb = fma4(aco, fv[1], sb);
                } else {
                    sa = fma4(aco, fja[j], sa);
                    sb = fma4(aco, fjb[j], sb);
                }
            }
        }
        Xn[t0] = sa;
        Xn[t1] = sb;
        if (resultOrNull) {
            ((f32x4*)(resultOrNull + prow))[t0] = sa;
            ((f32x4*)(resultOrNull + prow))[t1] = sb;
        }
#pragma unroll
        for (int i = 0; i < 2; i++) {
            const int p4 = (i == 0) ? t0 : t1;
            const f32x4 s = (i == 0) ? sa : sb;
            bf16x4 hh, ll;
#pragma unroll
            for (int q = 0; q < 4; q++) {
                float v = s[q];
                __bf16 h = (__bf16)v;
                hh[q] = h;
                ll[q] = (__bf16)(v - (float)h);
            }
            *(bf16x4*)&Ahi[prow + (size_t)p4 * 4] = hh;
            *(bf16x4*)&Alo[prow + (size_t)p4 * 4] = ll;
        }
    }
}

__global__ void finalize_kernel(const float* __restrict__ norms,
                                float* __restrict__ rel, float* __restrict__ absd)
{
    int t = threadIdx.x;
    if (t < NIT) {
        float a2 = 0.f, f2 = 0.f;
        for (int i = 0; i < 8; i++) {
            a2 += norms[t * 16 + i];
            f2 += norms[t * 16 + 8 + i];
        }
        float a = sqrtf(a2);
        absd[t] = a;
        rel[t] = a / (1e-5f + sqrtf(f2));
    }
}

extern "C" void kernel_launch(void* const* d_in, const int* in_sizes, int n_in,
                              void* d_out, int out_size, void* d_ws, size_t ws_size,
                              hipStream_t stream) {
    const float* x0   = (const float*)d_in[0];
    const float* W    = (const float*)d_in[1];
    const float* bias = (const float*)d_in[2];

    float* out    = (float*)d_out;
    float* result = out;
    float* Xout   = out + (size_t)BSZ * DIM;
    float* rel    = Xout + (size_t)BSZ * MS * DIM;
    float* absd   = rel + NIT;

    char* ws = (char*)d_ws;
    float* F     = (float*)ws;                                   // 100.66 MB
    float* norms = F + (size_t)BSZ * MS * DIM;                   // 2 KB (16*NIT used)
    float* GGt   = norms + 512;                                  // 288 KB
    float* P     = GGt + (size_t)BSZ * 36;                       // 33.55 MB (2 planes)
    char* p = (char*)(P + 2 * N2);
    size_t off = ((size_t)(p - ws) + 255) & ~(size_t)255;
    __bf16* Ahi  = (__bf16*)(ws + off);  off += (size_t)BSZ * DIM * 2;
    __bf16* Alo  = (__bf16*)(ws + off);  off += (size_t)BSZ * DIM * 2;
    __bf16* WThi = (__bf16*)(ws + off);  off += (size_t)DIM * DIM * 2;
    __bf16* WTlo = (__bf16*)(ws + off);  off += (size_t)DIM * DIM * 2;
    // G array (100.66 MB) only if scratch is big enough
    float* G = nullptr;
    if (ws_size >= off + (size_t)BSZ * MS * DIM * 4 + 256) {
        off = (off + 255) & ~(size_t)255;
        G = (float*)(ws + off);
    }

    wt_split_kernel<<<dim3(64, 64), 256, 0, stream>>>(W, WThi, WTlo);
    init_kernel<<<2048, 256, 0, stream>>>(x0, Xout, Ahi, Alo, norms);

    // mega_j consumes gemm_j's P (f(arg_j)) and produces xnew_{j+1}:
    //   j=0:   arg = x0            (norms not traced)
    //   j>=1:  arg = xnew_j        (norms -> iter j)
    for (int j = 0; j <= NIT; j++) {
        gemm_mfma_kernel<<<512, 256, 0, stream>>>(Ahi, Alo, WThi, WTlo, P);
        int up   = j % MS;
        int nact = (j < NIT) ? ((j + 1 < MS) ? (j + 1) : MS) : 0;
        int nxt  = (j < NIT) ? ((j + 1) % MS) : -1;
        mega_kernel<<<BSZ, 256, 0, stream>>>(P, bias, F, Xout, G, GGt, Ahi, Alo,
                                             (j == NIT - 1) ? result : nullptr,
                                             (j >= 1) ? (norms + 16 * (j - 1)) : nullptr,
                                             up, nact, nxt);
    }
    finalize_kernel<<<1, 64, 0, stream>>>(norms, rel, absd);
}